// Round 17
// baseline (208.208 us; speedup 1.0000x reference)
//
#include <hip/hip_runtime.h>
#include <math.h>

#define N_NODES 100000
#define N_EDGES 3200000
#define F_IN    37
#define H_DIM   16
#define C_DIM   2

#define BUCKET_BITS 7
#define BUCKET_SZ   128
#define NBUCK       782          // ceil(100000/128)
#define CAP         5760         // padded bucket capacity (mean ~4988 + 10 sigma), 8-mult
#define NPBLK       256          // k_part grid: one block per CU
#define EB          12500        // edges per part block (256*12500 = 3.2M exactly)
#define EPT         13           // ceil(12500/1024)
#define EPT_S       6            // ceil(CAP/1024)

__device__ __forceinline__ unsigned bf16rne(float f) {
    unsigned u = __float_as_uint(f);
    return (u + 0x7FFFu + ((u >> 16) & 1u)) >> 16;
}
__device__ __forceinline__ int2 ldnt_i2(const int2* p) {
    long long v = __builtin_nontemporal_load((const long long*)p);
    return *(int2*)&v;
}
#define BLO(u) __uint_as_float((u) << 16)
#define BHI(u) __uint_as_float((u) & 0xFFFF0000u)
// compact edge decode: u = (w_bf16 << 17) | row   (w in [0,1) => sign bit 0)
#define EW(u)  __uint_as_float(((u) >> 17) << 16)
#define ER(u)  ((u) & 0x1FFFFu)

// ---------- partition edges into destination buckets, 64B-aligned runs ----------
// Each (block,bucket) run is padded to a multiple of 8 edges (64 B): runs occupy
// whole cache lines only, killing the partial-line write-back amplification
// (R16 profile: 109 MB written for 25.6 MB payload). Pad slots hold (0,0)
// dummies (w bits == 0) which the sort kernel drops at load.
__global__ __launch_bounds__(1024) void k_part(
    const int* __restrict__ row, const int* __restrict__ col,
    const float* __restrict__ w, int* __restrict__ gcur, int2* __restrict__ ebuf)
{
    __shared__ int cnt[NBUCK];
    __shared__ int gbase[NBUCK];
    int t = threadIdx.x;
    size_t e0 = (size_t)blockIdx.x * EB;
    int bk[EPT], rc[EPT], lofs[EPT];
    float wv[EPT];

    if (t < NBUCK) cnt[t] = 0;
    __syncthreads();
#pragma unroll
    for (int k = 0; k < EPT; k++) {
        int i = k * 1024 + t;
        if (i < EB) {
            size_t e = e0 + i;
            int r = __builtin_nontemporal_load(&row[e]);
            int c = __builtin_nontemporal_load(&col[e]);
            wv[k] = __builtin_nontemporal_load(&w[e]);
            bk[k] = c >> BUCKET_BITS;
            rc[k] = r | ((c & (BUCKET_SZ - 1)) << 17);
            lofs[k] = atomicAdd(&cnt[bk[k]], 1);
        } else bk[k] = -1;
    }
    __syncthreads();
    if (t < NBUCK) {
        int res = (cnt[t] + 7) & ~7;              // pad run to 64 B
        gbase[t] = t * CAP + atomicAdd(&gcur[t], res);
    }
    __syncthreads();
#pragma unroll
    for (int k = 0; k < EPT; k++) {
        if (bk[k] >= 0)
            ebuf[gbase[bk[k]] + lofs[k]] = make_int2(rc[k], __float_as_int(wv[k]));
    }
    // fill pad slots with droppable dummies (w bits == 0)
    if (t < NBUCK) {
        int c0 = cnt[t];
        int pad = ((c0 + 7) & ~7) - c0;
        int base = gbase[t] + c0;
        for (int j = 0; j < pad; j++) ebuf[base + j] = make_int2(0, 0);
    }
}

// ---------- fused: per-bucket LDS counting sort (drops w==0 pads) ->
//            compact 4B edges + CSR + dinv + h1b = bf16(dinv*(x@W1)) ----------
__global__ __launch_bounds__(1024) void k_sortxw1(
    const int* __restrict__ gcur, const int2* __restrict__ ebuf,
    const float* __restrict__ x, const float* __restrict__ W1,
    unsigned* __restrict__ ebuf4, int2* __restrict__ rp,
    float* __restrict__ dinv, unsigned* __restrict__ h1b)
{
    __shared__ int2  stage[CAP];              // 46.1 KB (reused as xs below)
    __shared__ int   cnt[BUCKET_SZ];
    __shared__ int   base[BUCKET_SZ];
    __shared__ float sdinv[BUCKET_SZ];
    __shared__ float sW[F_IN * H_DIM];        // 2.4 KB
    float* xs = (float*)stage;                // aliased reuse: 128*37 floats

    int t = threadIdx.x, b = blockIdx.x;
    int s = b * CAP;
    int len = gcur[b];                        // padded length (memset base 0)
    int nbase = b << BUCKET_BITS;
    if (t < BUCKET_SZ) cnt[t] = 0;
    __syncthreads();

    // ---- load + count (drop pad records: w bits == 0) ----
    int2 ed[EPT_S]; int cl[EPT_S], lofs[EPT_S];
#pragma unroll
    for (int k = 0; k < EPT_S; k++) {
        int i = k * 1024 + t;
        cl[k] = -1;
        if (i < len) {
            int2 v = ldnt_i2(&ebuf[s + i]);
            if (v.y != 0) {                   // real edge (w=0 contributes nothing)
                ed[k] = v;
                cl[k] = v.x >> 17;
                lofs[k] = atomicAdd(&cnt[cl[k]], 1);
            }
        }
    }
    __syncthreads();
    // ---- inclusive scan of cnt[128] ----
    if (t < BUCKET_SZ) base[t] = cnt[t];
    __syncthreads();
    for (int off = 1; off < BUCKET_SZ; off <<= 1) {
        int v2 = 0;
        if (t < BUCKET_SZ && t >= off) v2 = base[t - off];
        __syncthreads();
        if (t < BUCKET_SZ) base[t] += v2;
        __syncthreads();
    }
    // ---- scatter into LDS stage in node-sorted order (compacted, pads gone) ----
#pragma unroll
    for (int k = 0; k < EPT_S; k++) {
        if (cl[k] >= 0) {
            int pos = base[cl[k]] - cnt[cl[k]] + lofs[k];
            stage[pos] = ed[k];
        }
    }
    __syncthreads();
    // ---- compact 4B write-back (NT, coalesced => full-line writes) ----
    {
        int total = base[BUCKET_SZ - 1];      // real edges in this bucket
        for (int i = t; i < total; i += 1024) {
            int2 v = stage[i];
            unsigned wb = bf16rne(__int_as_float(v.y));
            __builtin_nontemporal_store((wb << 17) | (unsigned)(v.x & 0x1FFFF),
                                        &ebuf4[s + i]);
        }
    }
    // ---- degree -> dinv: 8 threads/node strided + shfl reduce ----
    {
        int n = t >> 3, l = t & 7;
        int st = base[n] - cnt[n], cn = cnt[n];
        float sum = 0.f;
        for (int i = l; i < cn; i += 8) sum += __int_as_float(stage[st + i].y);
        sum += __shfl_xor(sum, 1);
        sum += __shfl_xor(sum, 2);
        sum += __shfl_xor(sum, 4);
        if (l == 0) {
            float di = rsqrtf(sum + 1.0f);    // + self-loop
            sdinv[n] = di;
            int c = nbase + n;
            if (c < N_NODES) {
                rp[c] = make_int2(s + st, cn);
                dinv[c] = di;
            }
        }
    }
    __syncthreads();                          // stage reads done; xs overwrite ok

    // ---- fused xw1 for this bucket's 128 nodes ----
    for (int idx = t; idx < F_IN * H_DIM; idx += 1024) sW[idx] = W1[idx];
    {
        const float4* x4 = (const float4*)(x + (size_t)nbase * F_IN);
        const int nv4 = (BUCKET_SZ * F_IN) / 4;   // 1184
        int gf0 = nbase * F_IN;
        for (int idx = t; idx < nv4; idx += 1024) {
            int gf = gf0 + 4 * idx;
            float4 v;
            if (gf + 3 < N_NODES * F_IN) {
                v = x4[idx];
            } else {
                v.x = (gf + 0 < N_NODES * F_IN) ? x[gf + 0] : 0.f;
                v.y = (gf + 1 < N_NODES * F_IN) ? x[gf + 1] : 0.f;
                v.z = (gf + 2 < N_NODES * F_IN) ? x[gf + 2] : 0.f;
                v.w = (gf + 3 < N_NODES * F_IN) ? x[gf + 3] : 0.f;
            }
            ((float4*)xs)[idx] = v;
        }
    }
    __syncthreads();
    // 8 threads/node, each computes 2 output cols {2*sub, 2*sub+1}
    {
        int n = t >> 3, sub = t & 7;
        int c = nbase + n;
        if (c < N_NODES) {
            const float* xi = &xs[n * F_IN];
            float a0 = 0.f, a1 = 0.f;
            for (int k = 0; k < F_IN; k++) {
                float xv = xi[k];
                a0 += xv * sW[k * H_DIM + 2 * sub];
                a1 += xv * sW[k * H_DIM + 2 * sub + 1];
            }
            float di = sdinv[n];
            unsigned pk = bf16rne(di * a0) | (bf16rne(di * a1) << 16);
            h1b[(size_t)c * 8 + sub] = pk;    // 32B/node, coalesced
        }
    }
}

// ---------- layer 1: 16 lanes/node (4 feature-quads x 4 segment-quarters),
//            8B gathers, shfl-combine, fused relu/bias + @W2 -> h2s ----------
__global__ __launch_bounds__(256) void k_agg1(
    const int2* __restrict__ rp, const unsigned* __restrict__ ebuf4,
    const uint2* __restrict__ h1b, const float* __restrict__ dinv,
    const float* __restrict__ b1, const float* __restrict__ W2,
    float* __restrict__ h2s)
{
    __shared__ float sW2[H_DIM * C_DIM];
    __shared__ float sb1[H_DIM];
    int t = threadIdx.x;
    if (t < H_DIM * C_DIM) sW2[t] = W2[t];
    if (t >= 32 && t < 32 + H_DIM) sb1[t - 32] = b1[t - 32];
    __syncthreads();
    int id = blockIdx.x * 256 + t;
    int c = id >> 4;                           // 16 lanes per node
    int sub = id & 15, q = sub & 3, h = sub >> 2;
    if (c >= N_NODES) return;
    int2 seg = rp[c];
    int s = seg.x, n = seg.y;
    int m = (n - h + 3) >> 2;                  // edges for this quarter (stride 4)
    int p0i = s + h;
    float4 acc = make_float4(0.f, 0.f, 0.f, 0.f);

#define PROC1(u)                                                    \
    {   float a = EW(u);                                            \
        uint2 g = h1b[(size_t)ER(u) * 4 + q];                       \
        acc.x += a * BLO(g.x); acc.y += a * BHI(g.x);               \
        acc.z += a * BLO(g.y); acc.w += a * BHI(g.y); }

    int k = 0;
    if (m >= 4) {
        unsigned e0 = __builtin_nontemporal_load(&ebuf4[p0i + 0]);
        unsigned e1 = __builtin_nontemporal_load(&ebuf4[p0i + 4]);
        unsigned e2 = __builtin_nontemporal_load(&ebuf4[p0i + 8]);
        unsigned e3 = __builtin_nontemporal_load(&ebuf4[p0i + 12]);
        for (; k + 8 <= m; k += 4) {
            unsigned f0 = __builtin_nontemporal_load(&ebuf4[p0i + 4 * (k + 4)]);
            unsigned f1 = __builtin_nontemporal_load(&ebuf4[p0i + 4 * (k + 5)]);
            unsigned f2 = __builtin_nontemporal_load(&ebuf4[p0i + 4 * (k + 6)]);
            unsigned f3 = __builtin_nontemporal_load(&ebuf4[p0i + 4 * (k + 7)]);
            PROC1(e0); PROC1(e1); PROC1(e2); PROC1(e3);
            e0 = f0; e1 = f1; e2 = f2; e3 = f3;
        }
        PROC1(e0); PROC1(e1); PROC1(e2); PROC1(e3);
        k += 4;
    }
    for (; k < m; k++) {
        unsigned u = __builtin_nontemporal_load(&ebuf4[p0i + 4 * k]);
        PROC1(u);
    }
#undef PROC1

    acc.x += __shfl_xor(acc.x, 4);  acc.x += __shfl_xor(acc.x, 8);
    acc.y += __shfl_xor(acc.y, 4);  acc.y += __shfl_xor(acc.y, 8);
    acc.z += __shfl_xor(acc.z, 4);  acc.z += __shfl_xor(acc.z, 8);
    acc.w += __shfl_xor(acc.w, 4);  acc.w += __shfl_xor(acc.w, 8);

    float dc = dinv[c];
    uint2 gc = h1b[(size_t)c * 4 + q];
    float hcv[4] = {BLO(gc.x), BHI(gc.x), BLO(gc.y), BHI(gc.y)};
    float av[4] = {acc.x + hcv[0], acc.y + hcv[1], acc.z + hcv[2], acc.w + hcv[3]};
    int j0 = q << 2;
    float p0 = 0.f, p1 = 0.f;
#pragma unroll
    for (int j = 0; j < 4; j++) {
        float rv = fmaxf(dc * av[j] + sb1[j0 + j], 0.f);
        p0 += rv * sW2[(j0 + j) * C_DIM + 0];
        p1 += rv * sW2[(j0 + j) * C_DIM + 1];
    }
    p0 += __shfl_xor(p0, 1); p0 += __shfl_xor(p0, 2);
    p1 += __shfl_xor(p1, 1); p1 += __shfl_xor(p1, 2);
    if (sub == 0) ((float2*)h2s)[c] = make_float2(dc * p0, dc * p1);
}

// ---------- layer 2: 8 lanes/node (segment eighths), shfl reduce,
//            + bias + log_softmax ----------
__global__ __launch_bounds__(256) void k_agg2(
    const int2* __restrict__ rp, const unsigned* __restrict__ ebuf4,
    const float* __restrict__ h2s, const float* __restrict__ dinv,
    const float* __restrict__ b2, float* __restrict__ out)
{
    int id = blockIdx.x * 256 + threadIdx.x;
    int c = id >> 3, sub = id & 7;
    if (c >= N_NODES) return;
    int2 seg = rp[c];
    int s = seg.x, n = seg.y;
    const float2* h22 = (const float2*)h2s;
    int m = (n - sub + 7) >> 3;                // edges for this eighth (stride 8)
    int p0i = s + sub;
    float a0 = 0.f, a1 = 0.f;

#define PROC2(u)                                                    \
    {   float a = EW(u);                                            \
        float2 hv = h22[ER(u)];                                     \
        a0 += a * hv.x;  a1 += a * hv.y; }

    int k = 0;
    if (m >= 4) {
        unsigned e0 = __builtin_nontemporal_load(&ebuf4[p0i + 0]);
        unsigned e1 = __builtin_nontemporal_load(&ebuf4[p0i + 8]);
        unsigned e2 = __builtin_nontemporal_load(&ebuf4[p0i + 16]);
        unsigned e3 = __builtin_nontemporal_load(&ebuf4[p0i + 24]);
        for (; k + 8 <= m; k += 4) {
            unsigned f0 = __builtin_nontemporal_load(&ebuf4[p0i + 8 * (k + 4)]);
            unsigned f1 = __builtin_nontemporal_load(&ebuf4[p0i + 8 * (k + 5)]);
            unsigned f2 = __builtin_nontemporal_load(&ebuf4[p0i + 8 * (k + 6)]);
            unsigned f3 = __builtin_nontemporal_load(&ebuf4[p0i + 8 * (k + 7)]);
            PROC2(e0); PROC2(e1); PROC2(e2); PROC2(e3);
            e0 = f0; e1 = f1; e2 = f2; e3 = f3;
        }
        PROC2(e0); PROC2(e1); PROC2(e2); PROC2(e3);
        k += 4;
    }
    for (; k < m; k++) {
        unsigned u = __builtin_nontemporal_load(&ebuf4[p0i + 8 * k]);
        PROC2(u);
    }
#undef PROC2

    a0 += __shfl_xor(a0, 1); a0 += __shfl_xor(a0, 2); a0 += __shfl_xor(a0, 4);
    a1 += __shfl_xor(a1, 1); a1 += __shfl_xor(a1, 2); a1 += __shfl_xor(a1, 4);
    if (sub == 0) {
        float dc = dinv[c];
        float2 hc = h22[c];
        float l0 = dc * (a0 + hc.x) + b2[0];
        float l1 = dc * (a1 + hc.y) + b2[1];
        float mx = fmaxf(l0, l1);
        float lse = mx + logf(expf(l0 - mx) + expf(l1 - mx));
        ((float2*)out)[c] = make_float2(l0 - lse, l1 - lse);
    }
}

extern "C" void kernel_launch(void* const* d_in, const int* in_sizes, int n_in,
                              void* d_out, int out_size, void* d_ws, size_t ws_size,
                              hipStream_t stream) {
    const float* x  = (const float*)d_in[0];
    const int*   ei = (const int*)d_in[1];     // [2, E]: row then col
    const float* w  = (const float*)d_in[2];
    const float* W1 = (const float*)d_in[3];
    const float* b1 = (const float*)d_in[4];
    const float* W2 = (const float*)d_in[5];
    const float* b2 = (const float*)d_in[6];
    float* out = (float*)d_out;

    const int* row = ei;
    const int* col = ei + N_EDGES;

    // workspace layout (64B-aligned offsets)
    char* ws = (char*)d_ws;
    int*      gcur  = (int*)(ws + 0);            //      3,200 B
    int2*     rp    = (int2*)(ws + 3200);        //    800,000 B
    float*    dinv  = (float*)(ws + 803200);     //    400,000 B
    unsigned* h1b   = (unsigned*)(ws + 1203200); //  3,200,000 B (bf16 16/row)
    float*    h2s   = (float*)(ws + 4403200);    //    800,000 B
    unsigned* ebuf4 = (unsigned*)(ws + 5203200); // 18,017,280 B (782*5760*4)
    int2*     ebuf  = (int2*)(ws + 23220480);    // 36,034,560 B (782*5760*8)
    // end: 59,255,040 B

    hipMemsetAsync(gcur, 0, 3200, stream);       // bucket counters = 0
    k_part    <<<NPBLK, 1024, 0, stream>>>(row, col, w, gcur, ebuf);
    k_sortxw1 <<<NBUCK, 1024, 0, stream>>>(gcur, ebuf, x, W1, ebuf4, rp, dinv, h1b);
    k_agg1    <<<(16 * N_NODES + 255) / 256, 256, 0, stream>>>(rp, ebuf4, (const uint2*)h1b, dinv, b1, W2, h2s);
    k_agg2    <<<(8 * N_NODES + 255) / 256, 256, 0, stream>>>(rp, ebuf4, h2s, dinv, b2, out);
}

// Round 18
// 196.358 us; speedup vs baseline: 1.0604x; 1.0604x over previous
//
#include <hip/hip_runtime.h>
#include <math.h>

#define N_NODES 100000
#define N_EDGES 3200000
#define F_IN    37
#define H_DIM   16
#define C_DIM   2

#define BUCKET_BITS 7
#define BUCKET_SZ   128
#define NBUCK       782          // ceil(100000/128)
#define CAP         4736         // bucket capacity: mean ~4092 + 10 sigma
#define NPBLK       512          // k_part grid (2 blocks/CU)
#define EB          6250         // edges per part block (512*6250 = 3.2M exactly)
#define EPT_P       7            // ceil(6250/1024)
#define EPT_S       5            // ceil(CAP/1024)

__device__ __forceinline__ unsigned bf16rne(float f) {
    unsigned u = __float_as_uint(f);
    return (u + 0x7FFFu + ((u >> 16) & 1u)) >> 16;
}
__device__ __forceinline__ int2 ldnt_i2(const int2* p) {
    long long v = __builtin_nontemporal_load((const long long*)p);
    return *(int2*)&v;
}
#define BLO(u) __uint_as_float((u) << 16)
#define BHI(u) __uint_as_float((u) & 0xFFFF0000u)
// compact edge decode: u = (w_bf16 << 17) | row   (w in [0,1) => sign bit 0)
#define EW(u)  __uint_as_float(((u) >> 17) << 16)
#define ER(u)  ((u) & 0x1FFFFu)

// ---------- partition: LDS-staged counting sort per chunk -> linear write-out.
// R16 disproved alignment as the cause of the 4x write amplification; the
// mechanism is TEMPORAL spread (one line filled by stores from different waves
// at different times -> partial write-backs). Staging the chunk in LDS sorted
// by bucket and sweeping it out linearly makes each line's bytes arrive
// back-to-back in time, letting L2 write each line once.
__global__ __launch_bounds__(1024) void k_part(
    const int* __restrict__ row, const int* __restrict__ col,
    const float* __restrict__ w, int* __restrict__ gcur, int2* __restrict__ ebuf)
{
    __shared__ int  cnt[NBUCK];
    __shared__ int  base[NBUCK];               // inclusive scan
    __shared__ int  gbase[NBUCK];
    __shared__ int2 stage[EB];                 // 50 KB
    int t = threadIdx.x;
    size_t e0 = (size_t)blockIdx.x * EB;
    int bk[EPT_P], rc[EPT_P], lofs[EPT_P];
    float wv[EPT_P];

    if (t < NBUCK) cnt[t] = 0;
    __syncthreads();
#pragma unroll
    for (int k = 0; k < EPT_P; k++) {
        int i = k * 1024 + t;
        if (i < EB) {
            size_t e = e0 + i;
            int r = __builtin_nontemporal_load(&row[e]);
            int c = __builtin_nontemporal_load(&col[e]);
            wv[k] = __builtin_nontemporal_load(&w[e]);
            bk[k] = c >> BUCKET_BITS;
            rc[k] = r | ((c & (BUCKET_SZ - 1)) << 17);
            lofs[k] = atomicAdd(&cnt[bk[k]], 1);
        } else bk[k] = -1;
    }
    __syncthreads();
    // inclusive scan of cnt[782] (10 Hillis-Steele rounds)
    if (t < NBUCK) base[t] = cnt[t];
    __syncthreads();
    for (int off = 1; off < 1024; off <<= 1) {
        int v = 0;
        if (t < NBUCK && t >= off) v = base[t - off];
        __syncthreads();
        if (t < NBUCK) base[t] += v;
        __syncthreads();
    }
    // scatter into LDS stage, bucket-sorted
#pragma unroll
    for (int k = 0; k < EPT_P; k++) {
        if (bk[k] >= 0)
            stage[base[bk[k]] - cnt[bk[k]] + lofs[k]] =
                make_int2(rc[k], __float_as_int(wv[k]));
    }
    if (t < NBUCK) gbase[t] = t * CAP + atomicAdd(&gcur[t], cnt[t]);
    __syncthreads();
    // linear sweep write-out: consecutive s -> consecutive dst within each run
    for (int s2 = t; s2 < EB; s2 += 1024) {
        int lo = 0, hi = NBUCK - 1;
        while (lo < hi) { int mid = (lo + hi) >> 1; if (base[mid] > s2) hi = mid; else lo = mid + 1; }
        int dst = gbase[lo] + (s2 - (base[lo] - cnt[lo]));
        ebuf[dst] = stage[s2];
    }
}

// ---------- fused: per-bucket LDS counting sort -> compact 4B edges + CSR
//            + dinv + h1b = bf16(dinv * (x @ W1)) for this bucket's nodes ----------
__global__ __launch_bounds__(1024) void k_sortxw1(
    const int* __restrict__ gcur, const int2* __restrict__ ebuf,
    const float* __restrict__ x, const float* __restrict__ W1,
    unsigned* __restrict__ ebuf4, int2* __restrict__ rp,
    float* __restrict__ dinv, unsigned* __restrict__ h1b)
{
    __shared__ int2  stage[CAP];              // 37.9 KB (reused as xs below)
    __shared__ int   cnt[BUCKET_SZ];
    __shared__ int   base[BUCKET_SZ];
    __shared__ float sdinv[BUCKET_SZ];
    __shared__ float sW[F_IN * H_DIM];        // 2.4 KB
    float* xs = (float*)stage;                // aliased reuse: 128*37 floats

    int t = threadIdx.x, b = blockIdx.x;
    int s = b * CAP;
    int len = gcur[b];                        // per-bucket count (memset base 0)
    int nbase = b << BUCKET_BITS;
    if (t < BUCKET_SZ) cnt[t] = 0;
    __syncthreads();

    // ---- load + count ----
    int2 ed[EPT_S]; int cl[EPT_S], lofs[EPT_S];
#pragma unroll
    for (int k = 0; k < EPT_S; k++) {
        int i = k * 1024 + t;
        if (i < len) {
            int2 v = ldnt_i2(&ebuf[s + i]);
            ed[k] = v;
            cl[k] = v.x >> 17;
            lofs[k] = atomicAdd(&cnt[cl[k]], 1);
        } else cl[k] = -1;
    }
    __syncthreads();
    // ---- inclusive scan of cnt[128] ----
    if (t < BUCKET_SZ) base[t] = cnt[t];
    __syncthreads();
    for (int off = 1; off < BUCKET_SZ; off <<= 1) {
        int v2 = 0;
        if (t < BUCKET_SZ && t >= off) v2 = base[t - off];
        __syncthreads();
        if (t < BUCKET_SZ) base[t] += v2;
        __syncthreads();
    }
    // ---- scatter into LDS stage in node-sorted order ----
#pragma unroll
    for (int k = 0; k < EPT_S; k++) {
        if (cl[k] >= 0) {
            int pos = base[cl[k]] - cnt[cl[k]] + lofs[k];
            stage[pos] = ed[k];
        }
    }
    __syncthreads();
    // ---- compact 4B write-back (NT, coalesced => full-line writes) ----
    for (int i = t; i < len; i += 1024) {
        int2 v = stage[i];
        unsigned wb = bf16rne(__int_as_float(v.y));
        __builtin_nontemporal_store((wb << 17) | (unsigned)(v.x & 0x1FFFF),
                                    &ebuf4[s + i]);
    }
    // ---- degree -> dinv: 8 threads/node strided + shfl reduce ----
    {
        int n = t >> 3, l = t & 7;
        int st = base[n] - cnt[n], cn = cnt[n];
        float sum = 0.f;
        for (int i = l; i < cn; i += 8) sum += __int_as_float(stage[st + i].y);
        sum += __shfl_xor(sum, 1);
        sum += __shfl_xor(sum, 2);
        sum += __shfl_xor(sum, 4);
        if (l == 0) {
            float di = rsqrtf(sum + 1.0f);    // + self-loop
            sdinv[n] = di;
            int c = nbase + n;
            if (c < N_NODES) {
                rp[c] = make_int2(s + st, cn);
                dinv[c] = di;
            }
        }
    }
    __syncthreads();                          // stage reads done; xs overwrite ok

    // ---- fused xw1 for this bucket's 128 nodes ----
    for (int idx = t; idx < F_IN * H_DIM; idx += 1024) sW[idx] = W1[idx];
    {
        const float4* x4 = (const float4*)(x + (size_t)nbase * F_IN);
        const int nv4 = (BUCKET_SZ * F_IN) / 4;   // 1184
        int gf0 = nbase * F_IN;
        for (int idx = t; idx < nv4; idx += 1024) {
            int gf = gf0 + 4 * idx;
            float4 v;
            if (gf + 3 < N_NODES * F_IN) {
                v = x4[idx];
            } else {
                v.x = (gf + 0 < N_NODES * F_IN) ? x[gf + 0] : 0.f;
                v.y = (gf + 1 < N_NODES * F_IN) ? x[gf + 1] : 0.f;
                v.z = (gf + 2 < N_NODES * F_IN) ? x[gf + 2] : 0.f;
                v.w = (gf + 3 < N_NODES * F_IN) ? x[gf + 3] : 0.f;
            }
            ((float4*)xs)[idx] = v;
        }
    }
    __syncthreads();
    // 8 threads/node, each computes 2 output cols {2*sub, 2*sub+1}
    {
        int n = t >> 3, sub = t & 7;
        int c = nbase + n;
        if (c < N_NODES) {
            const float* xi = &xs[n * F_IN];
            float a0 = 0.f, a1 = 0.f;
            for (int k = 0; k < F_IN; k++) {
                float xv = xi[k];
                a0 += xv * sW[k * H_DIM + 2 * sub];
                a1 += xv * sW[k * H_DIM + 2 * sub + 1];
            }
            float di = sdinv[n];
            unsigned pk = bf16rne(di * a0) | (bf16rne(di * a1) << 16);
            h1b[(size_t)c * 8 + sub] = pk;    // 32B/node, coalesced
        }
    }
}

// ---------- layer 1: 16 lanes/node (4 feature-quads x 4 segment-quarters),
//            8B gathers, shfl-combine, fused relu/bias + @W2 -> h2s ----------
__global__ __launch_bounds__(256) void k_agg1(
    const int2* __restrict__ rp, const unsigned* __restrict__ ebuf4,
    const uint2* __restrict__ h1b, const float* __restrict__ dinv,
    const float* __restrict__ b1, const float* __restrict__ W2,
    float* __restrict__ h2s)
{
    __shared__ float sW2[H_DIM * C_DIM];
    __shared__ float sb1[H_DIM];
    int t = threadIdx.x;
    if (t < H_DIM * C_DIM) sW2[t] = W2[t];
    if (t >= 32 && t < 32 + H_DIM) sb1[t - 32] = b1[t - 32];
    __syncthreads();
    int id = blockIdx.x * 256 + t;
    int c = id >> 4;                           // 16 lanes per node
    int sub = id & 15, q = sub & 3, h = sub >> 2;
    if (c >= N_NODES) return;
    int2 seg = rp[c];
    int s = seg.x, n = seg.y;
    int m = (n - h + 3) >> 2;                  // edges for this quarter (stride 4)
    int p0i = s + h;
    float4 acc = make_float4(0.f, 0.f, 0.f, 0.f);

#define PROC1(u)                                                    \
    {   float a = EW(u);                                            \
        uint2 g = h1b[(size_t)ER(u) * 4 + q];                       \
        acc.x += a * BLO(g.x); acc.y += a * BHI(g.x);               \
        acc.z += a * BLO(g.y); acc.w += a * BHI(g.y); }

    int k = 0;
    if (m >= 4) {
        unsigned e0 = __builtin_nontemporal_load(&ebuf4[p0i + 0]);
        unsigned e1 = __builtin_nontemporal_load(&ebuf4[p0i + 4]);
        unsigned e2 = __builtin_nontemporal_load(&ebuf4[p0i + 8]);
        unsigned e3 = __builtin_nontemporal_load(&ebuf4[p0i + 12]);
        for (; k + 8 <= m; k += 4) {
            unsigned f0 = __builtin_nontemporal_load(&ebuf4[p0i + 4 * (k + 4)]);
            unsigned f1 = __builtin_nontemporal_load(&ebuf4[p0i + 4 * (k + 5)]);
            unsigned f2 = __builtin_nontemporal_load(&ebuf4[p0i + 4 * (k + 6)]);
            unsigned f3 = __builtin_nontemporal_load(&ebuf4[p0i + 4 * (k + 7)]);
            PROC1(e0); PROC1(e1); PROC1(e2); PROC1(e3);
            e0 = f0; e1 = f1; e2 = f2; e3 = f3;
        }
        PROC1(e0); PROC1(e1); PROC1(e2); PROC1(e3);
        k += 4;
    }
    for (; k < m; k++) {
        unsigned u = __builtin_nontemporal_load(&ebuf4[p0i + 4 * k]);
        PROC1(u);
    }
#undef PROC1

    acc.x += __shfl_xor(acc.x, 4);  acc.x += __shfl_xor(acc.x, 8);
    acc.y += __shfl_xor(acc.y, 4);  acc.y += __shfl_xor(acc.y, 8);
    acc.z += __shfl_xor(acc.z, 4);  acc.z += __shfl_xor(acc.z, 8);
    acc.w += __shfl_xor(acc.w, 4);  acc.w += __shfl_xor(acc.w, 8);

    float dc = dinv[c];
    uint2 gc = h1b[(size_t)c * 4 + q];
    float hcv[4] = {BLO(gc.x), BHI(gc.x), BLO(gc.y), BHI(gc.y)};
    float av[4] = {acc.x + hcv[0], acc.y + hcv[1], acc.z + hcv[2], acc.w + hcv[3]};
    int j0 = q << 2;
    float p0 = 0.f, p1 = 0.f;
#pragma unroll
    for (int j = 0; j < 4; j++) {
        float rv = fmaxf(dc * av[j] + sb1[j0 + j], 0.f);
        p0 += rv * sW2[(j0 + j) * C_DIM + 0];
        p1 += rv * sW2[(j0 + j) * C_DIM + 1];
    }
    p0 += __shfl_xor(p0, 1); p0 += __shfl_xor(p0, 2);
    p1 += __shfl_xor(p1, 1); p1 += __shfl_xor(p1, 2);
    if (sub == 0) ((float2*)h2s)[c] = make_float2(dc * p0, dc * p1);
}

// ---------- layer 2: 8 lanes/node (segment eighths), shfl reduce,
//            + bias + log_softmax ----------
__global__ __launch_bounds__(256) void k_agg2(
    const int2* __restrict__ rp, const unsigned* __restrict__ ebuf4,
    const float* __restrict__ h2s, const float* __restrict__ dinv,
    const float* __restrict__ b2, float* __restrict__ out)
{
    int id = blockIdx.x * 256 + threadIdx.x;
    int c = id >> 3, sub = id & 7;
    if (c >= N_NODES) return;
    int2 seg = rp[c];
    int s = seg.x, n = seg.y;
    const float2* h22 = (const float2*)h2s;
    int m = (n - sub + 7) >> 3;                // edges for this eighth (stride 8)
    int p0i = s + sub;
    float a0 = 0.f, a1 = 0.f;

#define PROC2(u)                                                    \
    {   float a = EW(u);                                            \
        float2 hv = h22[ER(u)];                                     \
        a0 += a * hv.x;  a1 += a * hv.y; }

    int k = 0;
    if (m >= 4) {
        unsigned e0 = __builtin_nontemporal_load(&ebuf4[p0i + 0]);
        unsigned e1 = __builtin_nontemporal_load(&ebuf4[p0i + 8]);
        unsigned e2 = __builtin_nontemporal_load(&ebuf4[p0i + 16]);
        unsigned e3 = __builtin_nontemporal_load(&ebuf4[p0i + 24]);
        for (; k + 8 <= m; k += 4) {
            unsigned f0 = __builtin_nontemporal_load(&ebuf4[p0i + 8 * (k + 4)]);
            unsigned f1 = __builtin_nontemporal_load(&ebuf4[p0i + 8 * (k + 5)]);
            unsigned f2 = __builtin_nontemporal_load(&ebuf4[p0i + 8 * (k + 6)]);
            unsigned f3 = __builtin_nontemporal_load(&ebuf4[p0i + 8 * (k + 7)]);
            PROC2(e0); PROC2(e1); PROC2(e2); PROC2(e3);
            e0 = f0; e1 = f1; e2 = f2; e3 = f3;
        }
        PROC2(e0); PROC2(e1); PROC2(e2); PROC2(e3);
        k += 4;
    }
    for (; k < m; k++) {
        unsigned u = __builtin_nontemporal_load(&ebuf4[p0i + 8 * k]);
        PROC2(u);
    }
#undef PROC2

    a0 += __shfl_xor(a0, 1); a0 += __shfl_xor(a0, 2); a0 += __shfl_xor(a0, 4);
    a1 += __shfl_xor(a1, 1); a1 += __shfl_xor(a1, 2); a1 += __shfl_xor(a1, 4);
    if (sub == 0) {
        float dc = dinv[c];
        float2 hc = h22[c];
        float l0 = dc * (a0 + hc.x) + b2[0];
        float l1 = dc * (a1 + hc.y) + b2[1];
        float mx = fmaxf(l0, l1);
        float lse = mx + logf(expf(l0 - mx) + expf(l1 - mx));
        ((float2*)out)[c] = make_float2(l0 - lse, l1 - lse);
    }
}

extern "C" void kernel_launch(void* const* d_in, const int* in_sizes, int n_in,
                              void* d_out, int out_size, void* d_ws, size_t ws_size,
                              hipStream_t stream) {
    const float* x  = (const float*)d_in[0];
    const int*   ei = (const int*)d_in[1];     // [2, E]: row then col
    const float* w  = (const float*)d_in[2];
    const float* W1 = (const float*)d_in[3];
    const float* b1 = (const float*)d_in[4];
    const float* W2 = (const float*)d_in[5];
    const float* b2 = (const float*)d_in[6];
    float* out = (float*)d_out;

    const int* row = ei;
    const int* col = ei + N_EDGES;

    // workspace layout (64B-aligned offsets)
    char* ws = (char*)d_ws;
    int*      gcur  = (int*)(ws + 0);            //     3,200 B
    int2*     rp    = (int2*)(ws + 3200);        //   800,000 B
    float*    dinv  = (float*)(ws + 803200);     //   400,000 B
    unsigned* h1b   = (unsigned*)(ws + 1203200); // 3,200,000 B (bf16 16/row)
    float*    h2s   = (float*)(ws + 4403200);    //   800,000 B
    unsigned* ebuf4 = (unsigned*)(ws + 5203200); //14,814,208 B (782*4736*4)
    int2*     ebuf  = (int2*)(ws + 20017408);    //29,628,416 B (782*4736*8)
    // end: 49,645,824 B

    hipMemsetAsync(gcur, 0, 3200, stream);       // bucket counters = 0
    k_part    <<<NPBLK, 1024, 0, stream>>>(row, col, w, gcur, ebuf);
    k_sortxw1 <<<NBUCK, 1024, 0, stream>>>(gcur, ebuf, x, W1, ebuf4, rp, dinv, h1b);
    k_agg1    <<<(16 * N_NODES + 255) / 256, 256, 0, stream>>>(rp, ebuf4, (const uint2*)h1b, dinv, b1, W2, h2s);
    k_agg2    <<<(8 * N_NODES + 255) / 256, 256, 0, stream>>>(rp, ebuf4, h2s, dinv, b2, out);
}

// Round 19
// 193.419 us; speedup vs baseline: 1.0765x; 1.0152x over previous
//
#include <hip/hip_runtime.h>
#include <math.h>

#define N_NODES 100000
#define N_EDGES 3200000
#define F_IN    37
#define H_DIM   16
#define C_DIM   2

#define BUCKET_BITS 7
#define BUCKET_SZ   128
#define NBUCK       782          // ceil(100000/128)
#define CAP         4736         // bucket capacity: mean ~4092 + 10 sigma
#define NPBLK       512          // k_part grid (2 blocks/CU)
#define EB          6250         // edges per part block (512*6250 = 3.2M exactly)
#define EPT_P       7            // ceil(6250/1024)
#define EPT_S       5            // ceil(CAP/1024)

__device__ __forceinline__ unsigned bf16rne(float f) {
    unsigned u = __float_as_uint(f);
    return (u + 0x7FFFu + ((u >> 16) & 1u)) >> 16;
}
__device__ __forceinline__ int2 ldnt_i2(const int2* p) {
    long long v = __builtin_nontemporal_load((const long long*)p);
    return *(int2*)&v;
}
#define BLO(u) __uint_as_float((u) << 16)
#define BHI(u) __uint_as_float((u) & 0xFFFF0000u)
// compact edge decode: u = (w_bf16 << 17) | row   (w in [0,1) => sign bit 0)
#define EW(u)  __uint_as_float(((u) >> 17) << 16)
#define ER(u)  ((u) & 0x1FFFFu)

// ---------- partition: LDS-staged counting sort per chunk -> linear write-out.
// (R17 win: staging kills temporal write amplification — lines filled
// back-to-back in time, L2 writes each line once.)
__global__ __launch_bounds__(1024) void k_part(
    const int* __restrict__ row, const int* __restrict__ col,
    const float* __restrict__ w, int* __restrict__ gcur, int2* __restrict__ ebuf)
{
    __shared__ int  cnt[NBUCK];
    __shared__ int  base[NBUCK];               // inclusive scan
    __shared__ int  gbase[NBUCK];
    __shared__ int2 stage[EB];                 // 50 KB
    int t = threadIdx.x;
    size_t e0 = (size_t)blockIdx.x * EB;
    int bk[EPT_P], rc[EPT_P], lofs[EPT_P];
    float wv[EPT_P];

    if (t < NBUCK) cnt[t] = 0;
    __syncthreads();
#pragma unroll
    for (int k = 0; k < EPT_P; k++) {
        int i = k * 1024 + t;
        if (i < EB) {
            size_t e = e0 + i;
            int r = __builtin_nontemporal_load(&row[e]);
            int c = __builtin_nontemporal_load(&col[e]);
            wv[k] = __builtin_nontemporal_load(&w[e]);
            bk[k] = c >> BUCKET_BITS;
            rc[k] = r | ((c & (BUCKET_SZ - 1)) << 17);
            lofs[k] = atomicAdd(&cnt[bk[k]], 1);
        } else bk[k] = -1;
    }
    __syncthreads();
    // inclusive scan of cnt[782]
    if (t < NBUCK) base[t] = cnt[t];
    __syncthreads();
    for (int off = 1; off < 1024; off <<= 1) {
        int v = 0;
        if (t < NBUCK && t >= off) v = base[t - off];
        __syncthreads();
        if (t < NBUCK) base[t] += v;
        __syncthreads();
    }
    // scatter into LDS stage, bucket-sorted
#pragma unroll
    for (int k = 0; k < EPT_P; k++) {
        if (bk[k] >= 0)
            stage[base[bk[k]] - cnt[bk[k]] + lofs[k]] =
                make_int2(rc[k], __float_as_int(wv[k]));
    }
    if (t < NBUCK) gbase[t] = t * CAP + atomicAdd(&gcur[t], cnt[t]);
    __syncthreads();
    // linear sweep write-out
    for (int s2 = t; s2 < EB; s2 += 1024) {
        int lo = 0, hi = NBUCK - 1;
        while (lo < hi) { int mid = (lo + hi) >> 1; if (base[mid] > s2) hi = mid; else lo = mid + 1; }
        int dst = gbase[lo] + (s2 - (base[lo] - cnt[lo]));
        ebuf[dst] = stage[s2];
    }
}

// ---------- fused: per-bucket LDS counting sort -> compact 4B edges + CSR
//            + dinv + h1b = bf16(dinv * (x @ W1)) for this bucket's nodes ----------
__global__ __launch_bounds__(1024) void k_sortxw1(
    const int* __restrict__ gcur, const int2* __restrict__ ebuf,
    const float* __restrict__ x, const float* __restrict__ W1,
    unsigned* __restrict__ ebuf4, int2* __restrict__ rp,
    float* __restrict__ dinv, unsigned* __restrict__ h1b)
{
    __shared__ int2  stage[CAP];              // 37.9 KB (reused as xs below)
    __shared__ int   cnt[BUCKET_SZ];
    __shared__ int   base[BUCKET_SZ];
    __shared__ float sdinv[BUCKET_SZ];
    __shared__ float sW[F_IN * H_DIM];        // 2.4 KB
    float* xs = (float*)stage;                // aliased reuse: 128*37 floats

    int t = threadIdx.x, b = blockIdx.x;
    int s = b * CAP;
    int len = gcur[b];                        // per-bucket count (memset base 0)
    int nbase = b << BUCKET_BITS;
    if (t < BUCKET_SZ) cnt[t] = 0;
    __syncthreads();

    // ---- load + count ----
    int2 ed[EPT_S]; int cl[EPT_S], lofs[EPT_S];
#pragma unroll
    for (int k = 0; k < EPT_S; k++) {
        int i = k * 1024 + t;
        if (i < len) {
            int2 v = ldnt_i2(&ebuf[s + i]);
            ed[k] = v;
            cl[k] = v.x >> 17;
            lofs[k] = atomicAdd(&cnt[cl[k]], 1);
        } else cl[k] = -1;
    }
    __syncthreads();
    // ---- inclusive scan of cnt[128] ----
    if (t < BUCKET_SZ) base[t] = cnt[t];
    __syncthreads();
    for (int off = 1; off < BUCKET_SZ; off <<= 1) {
        int v2 = 0;
        if (t < BUCKET_SZ && t >= off) v2 = base[t - off];
        __syncthreads();
        if (t < BUCKET_SZ) base[t] += v2;
        __syncthreads();
    }
    // ---- scatter into LDS stage in node-sorted order ----
#pragma unroll
    for (int k = 0; k < EPT_S; k++) {
        if (cl[k] >= 0) {
            int pos = base[cl[k]] - cnt[cl[k]] + lofs[k];
            stage[pos] = ed[k];
        }
    }
    __syncthreads();
    // ---- compact 4B write-back (NT, coalesced => full-line writes) ----
    for (int i = t; i < len; i += 1024) {
        int2 v = stage[i];
        unsigned wb = bf16rne(__int_as_float(v.y));
        __builtin_nontemporal_store((wb << 17) | (unsigned)(v.x & 0x1FFFF),
                                    &ebuf4[s + i]);
    }
    // ---- degree -> dinv: 8 threads/node strided + shfl reduce ----
    {
        int n = t >> 3, l = t & 7;
        int st = base[n] - cnt[n], cn = cnt[n];
        float sum = 0.f;
        for (int i = l; i < cn; i += 8) sum += __int_as_float(stage[st + i].y);
        sum += __shfl_xor(sum, 1);
        sum += __shfl_xor(sum, 2);
        sum += __shfl_xor(sum, 4);
        if (l == 0) {
            float di = rsqrtf(sum + 1.0f);    // + self-loop
            sdinv[n] = di;
            int c = nbase + n;
            if (c < N_NODES) {
                rp[c] = make_int2(s + st, cn);
                dinv[c] = di;
            }
        }
    }
    __syncthreads();                          // stage reads done; xs overwrite ok

    // ---- fused xw1 for this bucket's 128 nodes ----
    for (int idx = t; idx < F_IN * H_DIM; idx += 1024) sW[idx] = W1[idx];
    {
        const float4* x4 = (const float4*)(x + (size_t)nbase * F_IN);
        const int nv4 = (BUCKET_SZ * F_IN) / 4;   // 1184
        int gf0 = nbase * F_IN;
        for (int idx = t; idx < nv4; idx += 1024) {
            int gf = gf0 + 4 * idx;
            float4 v;
            if (gf + 3 < N_NODES * F_IN) {
                v = x4[idx];
            } else {
                v.x = (gf + 0 < N_NODES * F_IN) ? x[gf + 0] : 0.f;
                v.y = (gf + 1 < N_NODES * F_IN) ? x[gf + 1] : 0.f;
                v.z = (gf + 2 < N_NODES * F_IN) ? x[gf + 2] : 0.f;
                v.w = (gf + 3 < N_NODES * F_IN) ? x[gf + 3] : 0.f;
            }
            ((float4*)xs)[idx] = v;
        }
    }
    __syncthreads();
    // 8 threads/node, each computes 2 output cols {2*sub, 2*sub+1}
    {
        int n = t >> 3, sub = t & 7;
        int c = nbase + n;
        if (c < N_NODES) {
            const float* xi = &xs[n * F_IN];
            float a0 = 0.f, a1 = 0.f;
            for (int k = 0; k < F_IN; k++) {
                float xv = xi[k];
                a0 += xv * sW[k * H_DIM + 2 * sub];
                a1 += xv * sW[k * H_DIM + 2 * sub + 1];
            }
            float di = sdinv[n];
            unsigned pk = bf16rne(di * a0) | (bf16rne(di * a1) << 16);
            h1b[(size_t)c * 8 + sub] = pk;    // 32B/node, coalesced
        }
    }
}

// ---------- layer 1: 16 lanes/node = 2 feature-halves x 8 segment-eighths.
// Same TLP as R13's proven shape (the R8 lesson: lane count is the knob that
// matters), but 16B uint4 gathers -> half the L2 requests per edge (2 vs 4).
__global__ __launch_bounds__(256) void k_agg1(
    const int2* __restrict__ rp, const unsigned* __restrict__ ebuf4,
    const uint4* __restrict__ h1b, const float* __restrict__ dinv,
    const float* __restrict__ b1, const float* __restrict__ W2,
    float* __restrict__ h2s)
{
    __shared__ float sW2[H_DIM * C_DIM];
    __shared__ float sb1[H_DIM];
    int t = threadIdx.x;
    if (t < H_DIM * C_DIM) sW2[t] = W2[t];
    if (t >= 32 && t < 32 + H_DIM) sb1[t - 32] = b1[t - 32];
    __syncthreads();
    int id = blockIdx.x * 256 + t;
    int c = id >> 4;                           // 16 lanes per node
    int sub = id & 15, q = sub & 1, h = sub >> 1;
    if (c >= N_NODES) return;
    int2 seg = rp[c];
    int s = seg.x, n = seg.y;
    int m = (n - h + 7) >> 3;                  // edges for this eighth (stride 8)
    int p0i = s + h;
    float acc[8] = {0.f, 0.f, 0.f, 0.f, 0.f, 0.f, 0.f, 0.f};

#define PROC1(u)                                                    \
    {   float a = EW(u);                                            \
        uint4 g = h1b[(size_t)ER(u) * 2 + q];                       \
        acc[0] += a * BLO(g.x); acc[1] += a * BHI(g.x);             \
        acc[2] += a * BLO(g.y); acc[3] += a * BHI(g.y);             \
        acc[4] += a * BLO(g.z); acc[5] += a * BHI(g.z);             \
        acc[6] += a * BLO(g.w); acc[7] += a * BHI(g.w); }

    int k = 0;
    if (m >= 4) {
        unsigned e0 = __builtin_nontemporal_load(&ebuf4[p0i + 0]);
        unsigned e1 = __builtin_nontemporal_load(&ebuf4[p0i + 8]);
        unsigned e2 = __builtin_nontemporal_load(&ebuf4[p0i + 16]);
        unsigned e3 = __builtin_nontemporal_load(&ebuf4[p0i + 24]);
        for (; k + 8 <= m; k += 4) {
            unsigned f0 = __builtin_nontemporal_load(&ebuf4[p0i + 8 * (k + 4)]);
            unsigned f1 = __builtin_nontemporal_load(&ebuf4[p0i + 8 * (k + 5)]);
            unsigned f2 = __builtin_nontemporal_load(&ebuf4[p0i + 8 * (k + 6)]);
            unsigned f3 = __builtin_nontemporal_load(&ebuf4[p0i + 8 * (k + 7)]);
            PROC1(e0); PROC1(e1); PROC1(e2); PROC1(e3);
            e0 = f0; e1 = f1; e2 = f2; e3 = f3;
        }
        PROC1(e0); PROC1(e1); PROC1(e2); PROC1(e3);
        k += 4;
    }
    for (; k < m; k++) {
        unsigned u = __builtin_nontemporal_load(&ebuf4[p0i + 8 * k]);
        PROC1(u);
    }
#undef PROC1

    // combine the 8 segment-eighths (sub bits 1-3)
#pragma unroll
    for (int j = 0; j < 8; j++) {
        acc[j] += __shfl_xor(acc[j], 2);
        acc[j] += __shfl_xor(acc[j], 4);
        acc[j] += __shfl_xor(acc[j], 8);
    }

    float dc = dinv[c];
    uint4 gc = h1b[(size_t)c * 2 + q];
    float hcv[8] = {BLO(gc.x), BHI(gc.x), BLO(gc.y), BHI(gc.y),
                    BLO(gc.z), BHI(gc.z), BLO(gc.w), BHI(gc.w)};
    int j0 = q << 3;
    float p0 = 0.f, p1 = 0.f;
#pragma unroll
    for (int j = 0; j < 8; j++) {
        float rv = fmaxf(dc * (acc[j] + hcv[j]) + sb1[j0 + j], 0.f);
        p0 += rv * sW2[(j0 + j) * C_DIM + 0];
        p1 += rv * sW2[(j0 + j) * C_DIM + 1];
    }
    // combine the two feature halves (sub bit 0)
    p0 += __shfl_xor(p0, 1);
    p1 += __shfl_xor(p1, 1);
    if (sub == 0) ((float2*)h2s)[c] = make_float2(dc * p0, dc * p1);
}

// ---------- layer 2: 8 lanes/node (segment eighths), shfl reduce,
//            + bias + log_softmax ----------
__global__ __launch_bounds__(256) void k_agg2(
    const int2* __restrict__ rp, const unsigned* __restrict__ ebuf4,
    const float* __restrict__ h2s, const float* __restrict__ dinv,
    const float* __restrict__ b2, float* __restrict__ out)
{
    int id = blockIdx.x * 256 + threadIdx.x;
    int c = id >> 3, sub = id & 7;
    if (c >= N_NODES) return;
    int2 seg = rp[c];
    int s = seg.x, n = seg.y;
    const float2* h22 = (const float2*)h2s;
    int m = (n - sub + 7) >> 3;                // edges for this eighth (stride 8)
    int p0i = s + sub;
    float a0 = 0.f, a1 = 0.f;

#define PROC2(u)                                                    \
    {   float a = EW(u);                                            \
        float2 hv = h22[ER(u)];                                     \
        a0 += a * hv.x;  a1 += a * hv.y; }

    int k = 0;
    if (m >= 4) {
        unsigned e0 = __builtin_nontemporal_load(&ebuf4[p0i + 0]);
        unsigned e1 = __builtin_nontemporal_load(&ebuf4[p0i + 8]);
        unsigned e2 = __builtin_nontemporal_load(&ebuf4[p0i + 16]);
        unsigned e3 = __builtin_nontemporal_load(&ebuf4[p0i + 24]);
        for (; k + 8 <= m; k += 4) {
            unsigned f0 = __builtin_nontemporal_load(&ebuf4[p0i + 8 * (k + 4)]);
            unsigned f1 = __builtin_nontemporal_load(&ebuf4[p0i + 8 * (k + 5)]);
            unsigned f2 = __builtin_nontemporal_load(&ebuf4[p0i + 8 * (k + 6)]);
            unsigned f3 = __builtin_nontemporal_load(&ebuf4[p0i + 8 * (k + 7)]);
            PROC2(e0); PROC2(e1); PROC2(e2); PROC2(e3);
            e0 = f0; e1 = f1; e2 = f2; e3 = f3;
        }
        PROC2(e0); PROC2(e1); PROC2(e2); PROC2(e3);
        k += 4;
    }
    for (; k < m; k++) {
        unsigned u = __builtin_nontemporal_load(&ebuf4[p0i + 8 * k]);
        PROC2(u);
    }
#undef PROC2

    a0 += __shfl_xor(a0, 1); a0 += __shfl_xor(a0, 2); a0 += __shfl_xor(a0, 4);
    a1 += __shfl_xor(a1, 1); a1 += __shfl_xor(a1, 2); a1 += __shfl_xor(a1, 4);
    if (sub == 0) {
        float dc = dinv[c];
        float2 hc = h22[c];
        float l0 = dc * (a0 + hc.x) + b2[0];
        float l1 = dc * (a1 + hc.y) + b2[1];
        float mx = fmaxf(l0, l1);
        float lse = mx + logf(expf(l0 - mx) + expf(l1 - mx));
        ((float2*)out)[c] = make_float2(l0 - lse, l1 - lse);
    }
}

extern "C" void kernel_launch(void* const* d_in, const int* in_sizes, int n_in,
                              void* d_out, int out_size, void* d_ws, size_t ws_size,
                              hipStream_t stream) {
    const float* x  = (const float*)d_in[0];
    const int*   ei = (const int*)d_in[1];     // [2, E]: row then col
    const float* w  = (const float*)d_in[2];
    const float* W1 = (const float*)d_in[3];
    const float* b1 = (const float*)d_in[4];
    const float* W2 = (const float*)d_in[5];
    const float* b2 = (const float*)d_in[6];
    float* out = (float*)d_out;

    const int* row = ei;
    const int* col = ei + N_EDGES;

    // workspace layout (64B-aligned offsets)
    char* ws = (char*)d_ws;
    int*      gcur  = (int*)(ws + 0);            //     3,200 B
    int2*     rp    = (int2*)(ws + 3200);        //   800,000 B
    float*    dinv  = (float*)(ws + 803200);     //   400,000 B
    unsigned* h1b   = (unsigned*)(ws + 1203200); // 3,200,000 B (bf16 16/row)
    float*    h2s   = (float*)(ws + 4403200);    //   800,000 B
    unsigned* ebuf4 = (unsigned*)(ws + 5203200); //14,814,208 B (782*4736*4)
    int2*     ebuf  = (int2*)(ws + 20017408);    //29,628,416 B (782*4736*8)
    // end: 49,645,824 B

    hipMemsetAsync(gcur, 0, 3200, stream);       // bucket counters = 0
    k_part    <<<NPBLK, 1024, 0, stream>>>(row, col, w, gcur, ebuf);
    k_sortxw1 <<<NBUCK, 1024, 0, stream>>>(gcur, ebuf, x, W1, ebuf4, rp, dinv, h1b);
    k_agg1    <<<(16 * N_NODES + 255) / 256, 256, 0, stream>>>(rp, ebuf4, (const uint4*)h1b, dinv, b1, W2, h2s);
    k_agg2    <<<(8 * N_NODES + 255) / 256, 256, 0, stream>>>(rp, ebuf4, h2s, dinv, b2, out);
}